// Round 2
// baseline (483.869 us; speedup 1.0000x reference)
//
#include <hip/hip_runtime.h>

// GCN forward on MI355X (gfx950). Inputs/outputs are float32 (per reference).
// Internally: bf16 MFMA GEMMs (fp32 accum), bf16 intermediates S1/H/S2 to halve
// SpMM gather traffic, fp32 SpMM accumulation, fp32 log_softmax output.
// Pipeline: CSR build (count/scan/scatter) -> gemm1 -> spmm1+bias+relu
//           -> gemm2 -> spmm2+bias+log_softmax.

typedef unsigned short u16;
typedef __attribute__((ext_vector_type(8))) short bf16x8;   // 8 bf16 in 4 VGPRs
typedef __attribute__((ext_vector_type(4))) float f32x4;

#define N_NODES 50000
#define N_EDGES 800000
#define NFEAT 512
#define NHID 256
#define NCLASS 64

__device__ __forceinline__ float bf2f(u16 h) {
    union { unsigned u; float f; } cv; cv.u = ((unsigned)h) << 16; return cv.f;
}
__device__ __forceinline__ u16 f2bf(float f) {
    union { float f; unsigned u; } cv; cv.f = f;
    unsigned u = cv.u;
    return (u16)((u + 0x7fffu + ((u >> 16) & 1u)) >> 16);   // RNE
}

// ---------------- CSR build ----------------

__global__ void count_kernel(const int* __restrict__ dst, int* __restrict__ deg, int E) {
    int e = blockIdx.x * blockDim.x + threadIdx.x;
    if (e < E) atomicAdd(&deg[dst[e]], 1);
}

// single-block chunked exclusive scan: deg[0..n) -> rowstart[0..n], fill[i]=rowstart[i]
__global__ __launch_bounds__(1024) void scan_kernel(const int* __restrict__ deg,
                                                    int* __restrict__ rowstart,
                                                    int* __restrict__ fill, int n) {
    __shared__ int sh[1024];
    __shared__ int s_running;
    const int tid = threadIdx.x;
    if (tid == 0) s_running = 0;
    __syncthreads();
    const int CH = 4;
    for (int base = 0; base < n; base += 1024 * CH) {
        int i0 = base + tid * CH;
        int v[CH]; int s = 0;
        #pragma unroll
        for (int j = 0; j < CH; ++j) {
            int i = i0 + j;
            v[j] = (i < n) ? deg[i] : 0;
            s += v[j];
        }
        sh[tid] = s;
        __syncthreads();
        for (int off = 1; off < 1024; off <<= 1) {
            int t = (tid >= off) ? sh[tid - off] : 0;
            __syncthreads();
            sh[tid] += t;
            __syncthreads();
        }
        int incl = sh[tid];
        int run = s_running;
        int pre = run + incl - s;        // exclusive prefix for this thread's chunk
        #pragma unroll
        for (int j = 0; j < CH; ++j) {
            int i = i0 + j;
            if (i < n) { rowstart[i] = pre; fill[i] = pre; }
            pre += v[j];
        }
        __syncthreads();
        if (tid == 1023) s_running = run + incl;   // incl of last thread = chunk total
        __syncthreads();
    }
    if (tid == 0) rowstart[n] = s_running;
}

__global__ void scatter_kernel(const int* __restrict__ src, const int* __restrict__ dst,
                               const float* __restrict__ w, int* __restrict__ fill,
                               int* __restrict__ csr_src, float* __restrict__ csr_w, int E) {
    int e = blockIdx.x * blockDim.x + threadIdx.x;
    if (e < E) {
        int d = dst[e];
        int p = atomicAdd(&fill[d], 1);
        csr_src[p] = src[e];
        csr_w[p] = w[e];
    }
}

// ---------------- GEMM: C[M,N] = A[M,K] @ B[K,N] ----------------
// A: f32 or bf16 (template). B: f32 (converted to bf16 during LDS staging).
// C written as bf16. fp32 accumulation in MFMA.
// 64x64 block tile, 4 waves (each wave: 16 rows x 64 cols = 4 mfma_16x16x32 tiles).

template <bool A_IS_BF16>
__global__ __launch_bounds__(256) void gemm_mfma(const void* __restrict__ Aptr,
                                                 const float* __restrict__ B,
                                                 u16* __restrict__ C,
                                                 int M, int N, int K) {
    __shared__ __align__(16) u16 As[64][40];   // [m][k], +8 pad (80B row stride, 16B aligned)
    __shared__ __align__(16) u16 Bs[64][40];   // transposed: [n][k]

    const int tid  = threadIdx.x;
    const int wave = tid >> 6;
    const int lane = tid & 63;
    const int lm   = lane & 15;
    const int quad = lane >> 4;
    const int bm0  = blockIdx.y * 64;
    const int bn0  = blockIdx.x * 64;

    f32x4 acc[4];
    #pragma unroll
    for (int c = 0; c < 4; ++c) acc[c] = (f32x4){0.f, 0.f, 0.f, 0.f};

    const int a_row = tid >> 2;           // 0..63
    const int a_col = (tid & 3) << 3;     // 0,8,16,24 (8 k-elements per thread)
    const int b_row = tid >> 3;           // 0..31 (k)
    const int b_col = (tid & 7) << 3;     // 0..56 (n, 8 per thread)
    const bool a_ok = (bm0 + a_row) < M;

    const u16*   a_gp16 = (const u16*)Aptr   + (size_t)(bm0 + a_row) * K + a_col;
    const float* a_gp32 = (const float*)Aptr + (size_t)(bm0 + a_row) * K + a_col;
    const float* b_gp   = B + (size_t)b_row * N + bn0 + b_col;

    for (int k0 = 0; k0 < K; k0 += 32) {
        u16 a_tmp[8];
        if (A_IS_BF16) {
            int4 av = make_int4(0, 0, 0, 0);
            if (a_ok) av = *(const int4*)(a_gp16 + k0);
            *(int4*)a_tmp = av;
        } else {
            float4 f0 = make_float4(0.f, 0.f, 0.f, 0.f), f1 = f0;
            if (a_ok) {
                f0 = *(const float4*)(a_gp32 + k0);
                f1 = *(const float4*)(a_gp32 + k0 + 4);
            }
            a_tmp[0] = f2bf(f0.x); a_tmp[1] = f2bf(f0.y);
            a_tmp[2] = f2bf(f0.z); a_tmp[3] = f2bf(f0.w);
            a_tmp[4] = f2bf(f1.x); a_tmp[5] = f2bf(f1.y);
            a_tmp[6] = f2bf(f1.z); a_tmp[7] = f2bf(f1.w);
        }
        float4 g0 = *(const float4*)(b_gp + (size_t)k0 * N);
        float4 g1 = *(const float4*)(b_gp + (size_t)k0 * N + 4);
        u16 b_tmp[8];
        b_tmp[0] = f2bf(g0.x); b_tmp[1] = f2bf(g0.y);
        b_tmp[2] = f2bf(g0.z); b_tmp[3] = f2bf(g0.w);
        b_tmp[4] = f2bf(g1.x); b_tmp[5] = f2bf(g1.y);
        b_tmp[6] = f2bf(g1.z); b_tmp[7] = f2bf(g1.w);

        __syncthreads();   // previous iter's frag reads done
        *(int4*)&As[a_row][a_col] = *(int4*)a_tmp;
        #pragma unroll
        for (int i = 0; i < 8; ++i) Bs[b_col + i][b_row] = b_tmp[i];
        __syncthreads();

        bf16x8 af = *(const bf16x8*)&As[wave * 16 + lm][quad * 8];
        #pragma unroll
        for (int c = 0; c < 4; ++c) {
            bf16x8 bfv = *(const bf16x8*)&Bs[c * 16 + lm][quad * 8];
            acc[c] = __builtin_amdgcn_mfma_f32_16x16x32_bf16(af, bfv, acc[c], 0, 0, 0);
        }
    }

    #pragma unroll
    for (int c = 0; c < 4; ++c) {
        #pragma unroll
        for (int r = 0; r < 4; ++r) {
            int row = bm0 + wave * 16 + quad * 4 + r;   // C/D: row = quad*4+reg
            if (row < M) {
                int col = bn0 + c * 16 + lm;            // C/D: col = lane&15
                C[(size_t)row * N + col] = f2bf(acc[c][r]);
            }
        }
    }
}

// ---------------- SpMM1 + bias + ReLU (F=256, one wave per node, 4 feats/lane) ----------------

__global__ __launch_bounds__(256) void spmm_bias_relu_kernel(
    const u16* __restrict__ S, const int* __restrict__ rowstart,
    const int* __restrict__ csr_src, const float* __restrict__ csr_w,
    const float* __restrict__ bias, u16* __restrict__ H, int n) {
    int node = blockIdx.x * 4 + (threadIdx.x >> 6);
    if (node >= n) return;
    int lane = threadIdx.x & 63;
    int beg = rowstart[node], end = rowstart[node + 1];
    float a0 = 0.f, a1 = 0.f, a2 = 0.f, a3 = 0.f;
    int j = beg;
    for (; j + 2 <= end; j += 2) {           // 2-way unroll: 2 outstanding gathers
        int   s0 = csr_src[j],  s1 = csr_src[j + 1];
        float w0 = csr_w[j],    w1 = csr_w[j + 1];
        ushort4 v0 = *(const ushort4*)(S + (size_t)s0 * NHID + lane * 4);
        ushort4 v1 = *(const ushort4*)(S + (size_t)s1 * NHID + lane * 4);
        a0 += w0 * bf2f(v0.x) + w1 * bf2f(v1.x);
        a1 += w0 * bf2f(v0.y) + w1 * bf2f(v1.y);
        a2 += w0 * bf2f(v0.z) + w1 * bf2f(v1.z);
        a3 += w0 * bf2f(v0.w) + w1 * bf2f(v1.w);
    }
    if (j < end) {
        int s0 = csr_src[j]; float w0 = csr_w[j];
        ushort4 v0 = *(const ushort4*)(S + (size_t)s0 * NHID + lane * 4);
        a0 += w0 * bf2f(v0.x); a1 += w0 * bf2f(v0.y);
        a2 += w0 * bf2f(v0.z); a3 += w0 * bf2f(v0.w);
    }
    float4 bv = *(const float4*)(bias + lane * 4);
    a0 = fmaxf(a0 + bv.x, 0.f);
    a1 = fmaxf(a1 + bv.y, 0.f);
    a2 = fmaxf(a2 + bv.z, 0.f);
    a3 = fmaxf(a3 + bv.w, 0.f);
    ushort4 o;
    o.x = f2bf(a0); o.y = f2bf(a1); o.z = f2bf(a2); o.w = f2bf(a3);
    *(ushort4*)(H + (size_t)node * NHID + lane * 4) = o;
}

// ---------------- SpMM2 + bias + log_softmax (F=64, one wave per node, 1 class/lane) ----------------

__global__ __launch_bounds__(256) void spmm_bias_lsm_kernel(
    const u16* __restrict__ S, const int* __restrict__ rowstart,
    const int* __restrict__ csr_src, const float* __restrict__ csr_w,
    const float* __restrict__ bias, float* __restrict__ out, int n) {
    int node = blockIdx.x * 4 + (threadIdx.x >> 6);
    if (node >= n) return;
    int lane = threadIdx.x & 63;
    int beg = rowstart[node], end = rowstart[node + 1];
    float acc = 0.f;
    int j = beg;
    for (; j + 2 <= end; j += 2) {
        int   s0 = csr_src[j],  s1 = csr_src[j + 1];
        float w0 = csr_w[j],    w1 = csr_w[j + 1];
        float v0 = bf2f(S[(size_t)s0 * NCLASS + lane]);
        float v1 = bf2f(S[(size_t)s1 * NCLASS + lane]);
        acc += w0 * v0 + w1 * v1;
    }
    if (j < end) acc += csr_w[j] * bf2f(S[(size_t)csr_src[j] * NCLASS + lane]);

    float x = acc + bias[lane];
    float m = x;
    #pragma unroll
    for (int off = 32; off > 0; off >>= 1) m = fmaxf(m, __shfl_xor(m, off));
    float e = expf(x - m);
    float ssum = e;
    #pragma unroll
    for (int off = 32; off > 0; off >>= 1) ssum += __shfl_xor(ssum, off);
    out[(size_t)node * NCLASS + lane] = x - m - logf(ssum);
}

// ---------------- launch ----------------

extern "C" void kernel_launch(void* const* d_in, const int* in_sizes, int n_in,
                              void* d_out, int out_size, void* d_ws, size_t ws_size,
                              hipStream_t stream) {
    const float* x   = (const float*)d_in[0];   // [50000,512] f32
    const float* W1  = (const float*)d_in[1];   // [512,256]
    const float* b1  = (const float*)d_in[2];   // [256]
    const float* W2  = (const float*)d_in[3];   // [256,64]
    const float* b2  = (const float*)d_in[4];   // [64]
    const float* ew  = (const float*)d_in[5];   // [800000]
    const int* esrc = (const int*)d_in[6];      // [800000]
    const int* edst = (const int*)d_in[7];      // [800000]
    float* out = (float*)d_out;                 // [50000,64] f32

    char* ws = (char*)d_ws;
    size_t off = 0;
    auto take = [&](size_t bytes) -> void* {
        off = (off + 255) & ~(size_t)255;
        void* p = ws + off;
        off += bytes;
        return p;
    };
    u16*   S1       = (u16*)  take((size_t)N_NODES * NHID * 2);    // 25.6 MB bf16
    u16*   H        = (u16*)  take((size_t)N_NODES * NHID * 2);    // 25.6 MB bf16
    u16*   S2       = (u16*)  take((size_t)N_NODES * NCLASS * 2);  // 6.4 MB bf16
    int*   deg      = (int*)  take((size_t)N_NODES * 4);
    int*   rowstart = (int*)  take((size_t)(N_NODES + 1) * 4);
    int*   fill     = (int*)  take((size_t)N_NODES * 4);
    int*   csr_src  = (int*)  take((size_t)N_EDGES * 4);
    float* csr_w    = (float*)take((size_t)N_EDGES * 4);
    (void)ws_size; (void)in_sizes; (void)n_in; (void)out_size;

    // CSR build
    hipMemsetAsync(deg, 0, (size_t)N_NODES * 4, stream);
    count_kernel<<<(N_EDGES + 255) / 256, 256, 0, stream>>>(edst, deg, N_EDGES);
    scan_kernel<<<1, 1024, 0, stream>>>(deg, rowstart, fill, N_NODES);
    scatter_kernel<<<(N_EDGES + 255) / 256, 256, 0, stream>>>(esrc, edst, ew, fill,
                                                              csr_src, csr_w, N_EDGES);

    // layer 1: S1 = x @ W1 (bf16 MFMA), H = relu(A*S1 + b1)
    gemm_mfma<false><<<dim3(NHID / 64, (N_NODES + 63) / 64), 256, 0, stream>>>(
        (const void*)x, W1, S1, N_NODES, NHID, NFEAT);
    spmm_bias_relu_kernel<<<(N_NODES + 3) / 4, 256, 0, stream>>>(
        S1, rowstart, csr_src, csr_w, b1, H, N_NODES);

    // layer 2: S2 = H @ W2, out = log_softmax(A*S2 + b2)
    gemm_mfma<true><<<dim3(NCLASS / 64, (N_NODES + 63) / 64), 256, 0, stream>>>(
        (const void*)H, W2, S2, N_NODES, NCLASS, NHID);
    spmm_bias_lsm_kernel<<<(N_NODES + 3) / 4, 256, 0, stream>>>(
        S2, rowstart, csr_src, csr_w, b2, out, N_NODES);
}

// Round 4
// 422.255 us; speedup vs baseline: 1.1459x; 1.1459x over previous
//
#include <hip/hip_runtime.h>
#include <cstdint>

// GCN forward on MI355X (gfx950). f32 in/out; bf16 MFMA GEMMs with fp32 accum;
// bf16 intermediates (S1/H/S2) to halve SpMM gather bytes.
// Pipeline: transpose W1/W2 -> CSR build -> gemm1 -> spmm1+bias+relu
//           -> gemm2 -> spmm2+bias+log_softmax.

typedef unsigned short u16;
typedef unsigned int u32;
typedef __attribute__((ext_vector_type(8))) short bf16x8;
typedef __attribute__((ext_vector_type(4))) float f32x4;

#define N_NODES 50000
#define N_EDGES 800000
#define NFEAT 512
#define NHID 256
#define NCLASS 64
#define DEG_PAD 57344   // N_NODES rounded up to 8192 multiple (scan reads unguarded)

__device__ __forceinline__ float bf2f(u16 h) {
    union { u32 u; float f; } c; c.u = ((u32)h) << 16; return c.f;
}
__device__ __forceinline__ u16 f2bf(float f) {
    union { float f; u32 u; } c; c.f = f;
    u32 u = c.u;
    return (u16)((u + 0x7fffu + ((u >> 16) & 1u)) >> 16);   // RNE
}
__device__ __forceinline__ u32 pk2(float a, float b) {
    return (u32)f2bf(a) | ((u32)f2bf(b) << 16);
}

// async global->LDS, 16B per lane. LDS dest semantics: wave-uniform base + lane*16
// (our chunk indexing satisfies this). Addrspace casts via uintptr_t (CK pattern).
__device__ __forceinline__ void async16(const void* g, void* l) {
    __builtin_amdgcn_global_load_lds(
        (const __attribute__((address_space(1))) void*)(uintptr_t)g,
        (__attribute__((address_space(3))) void*)(uintptr_t)l, 16, 0, 0);
}

// ---------------- weight transpose+convert: out[n][k] = bf16(in[k][n]) ----------------

__global__ void transpose_cvt(const float* __restrict__ in, u16* __restrict__ out,
                              int Kd, int Nd) {
    int idx = blockIdx.x * blockDim.x + threadIdx.x;   // over out, write-coalesced
    if (idx < Kd * Nd) {
        int n = idx / Kd, k = idx - n * Kd;
        out[idx] = f2bf(in[(size_t)k * Nd + n]);
    }
}

// ---------------- CSR build ----------------

__global__ void count_kernel(const int* __restrict__ dst, int* __restrict__ deg, int E) {
    int e = blockIdx.x * blockDim.x + threadIdx.x;
    if (e < E) atomicAdd(&deg[dst[e]], 1);
}

// shuffle-based single-block scan: deg[0..n) -> rowstart[0..n], fill[i]=rowstart[i]
__global__ __launch_bounds__(1024) void scan_kernel(const int* __restrict__ deg,
                                                    int* __restrict__ rowstart,
                                                    int* __restrict__ fill, int n) {
    __shared__ int wsum[16];
    __shared__ int s_carry;
    const int tid = threadIdx.x;
    const int lane = tid & 63, wid = tid >> 6;
    if (tid == 0) s_carry = 0;
    __syncthreads();
    const int CH = 8;
    for (int base = 0; base < n; base += 1024 * CH) {
        int i0 = base + tid * CH;
        int4 va = *(const int4*)(deg + i0);        // deg zero-padded to DEG_PAD
        int4 vb = *(const int4*)(deg + i0 + 4);
        int v[CH] = {va.x, va.y, va.z, va.w, vb.x, vb.y, vb.z, vb.w};
        int s = 0;
        #pragma unroll
        for (int j = 0; j < CH; ++j) s += v[j];
        int incl = s;
        #pragma unroll
        for (int off = 1; off < 64; off <<= 1) {
            int t = __shfl_up(incl, off);
            if (lane >= off) incl += t;
        }
        if (lane == 63) wsum[wid] = incl;
        __syncthreads();
        if (wid == 0) {
            int ws = (lane < 16) ? wsum[lane] : 0;
            #pragma unroll
            for (int off = 1; off < 16; off <<= 1) {
                int t = __shfl_up(ws, off);
                if (lane >= off) ws += t;
            }
            if (lane < 16) wsum[lane] = ws;
        }
        __syncthreads();
        int carry = s_carry + ((wid > 0) ? wsum[wid - 1] : 0);
        int pre = carry + incl - s;   // exclusive prefix for this thread's chunk
        #pragma unroll
        for (int j = 0; j < CH; ++j) {
            int i = i0 + j;
            if (i < n) { rowstart[i] = pre; fill[i] = pre; }
            pre += v[j];
        }
        __syncthreads();
        // FIX (round 3 bug): new carry = carry + incl (wave-15 inclusive total),
        // NOT carry + s (thread 1023's chunk only — dropped lanes 0..62 of wave 15).
        if (tid == 1023) s_carry = carry + incl;
        __syncthreads();
    }
    if (tid == 0) rowstart[n] = s_carry;
}

__global__ void scatter_kernel(const int* __restrict__ src, const int* __restrict__ dst,
                               const float* __restrict__ w, int* __restrict__ fill,
                               int2* __restrict__ csr, int E) {
    int e = blockIdx.x * blockDim.x + threadIdx.x;
    if (e < E) {
        int p = atomicAdd(&fill[dst[e]], 1);
        csr[p] = make_int2(src[e], __float_as_int(w[e]));
    }
}

// ---------------- GEMM: C[M,NT] = A[M,K] @ B[K,NT], B given transposed bf16 [NT][K] ----------------
// Block tile MT x NT (NT = full N so A is fetched once). 4 waves in WROWSxWCOLS grid,
// each wave computes 64x(NT/WCOLS) via 4xCT mfma_16x16x32_bf16 tiles, BK=64 (2 k-halves).
// B (and A when bf16) staged via global_load_lds dwordx4; f32 A staged via load+cvt+ds_write.
// Epilogue repacks C tile through LDS for coalesced dwordx4 stores.

template <int MT, int NT, int WCOLS, bool A_BF16, int K>
__global__ __launch_bounds__(256) void gemm_bt(const void* __restrict__ Aptr,
                                               const u16* __restrict__ BT,
                                               u16* __restrict__ C, int M) {
    constexpr int WROWS = 4 / WCOLS;
    constexpr int RT = MT / (16 * WROWS);   // row tiles per wave (=4)
    constexpr int CT = NT / (16 * WCOLS);   // col tiles per wave
    __shared__ __align__(16) u16 lds[MT * 64 + NT * 64];
    u16* As = lds;             // [MT][64] contiguous (128 B rows)
    u16* Bs = lds + MT * 64;   // [NT][64] contiguous (B^T layout: row n, k-contig)

    const int tid  = threadIdx.x;
    const int wv   = tid >> 6, lane = tid & 63;
    const int lm   = lane & 15, quad = lane >> 4;
    const int wrow = wv / WCOLS, wcol = wv % WCOLS;
    const int m0   = blockIdx.x * MT;

    f32x4 acc[RT][CT];
    #pragma unroll
    for (int r = 0; r < RT; ++r)
        #pragma unroll
        for (int c = 0; c < CT; ++c) acc[r][c] = (f32x4){0.f, 0.f, 0.f, 0.f};

    for (int k0 = 0; k0 < K; k0 += 64) {
        // stage B^T tile: NT rows x 64 k (NT/32 chunks of 4 KB)
        #pragma unroll
        for (int i = 0; i < NT / 32; ++i) {
            int c = i * 256 + tid;
            int n = c >> 3, ko = (c & 7) * 8;
            async16(BT + (size_t)n * K + k0 + ko, Bs + c * 8);
        }
        if (A_BF16) {
            #pragma unroll
            for (int i = 0; i < MT / 32; ++i) {
                int c = i * 256 + tid;
                int row = c >> 3, ko = (c & 7) * 8;
                int gr = m0 + row; if (gr > M - 1) gr = M - 1;
                async16((const u16*)Aptr + (size_t)gr * K + k0 + ko, As + c * 8);
            }
        } else {
            // MT == 64 path: thread stages 16 f32 -> 16 bf16 (row = tid/4)
            int row = tid >> 2, ko = (tid & 3) * 16;
            int gr = m0 + row; if (gr > M - 1) gr = M - 1;
            const float4* gp = (const float4*)((const float*)Aptr + (size_t)gr * K + k0 + ko);
            float4 f0 = gp[0], f1 = gp[1], f2 = gp[2], f3 = gp[3];
            u32 p[8] = {pk2(f0.x, f0.y), pk2(f0.z, f0.w), pk2(f1.x, f1.y), pk2(f1.z, f1.w),
                        pk2(f2.x, f2.y), pk2(f2.z, f2.w), pk2(f3.x, f3.y), pk2(f3.z, f3.w)};
            u32* dp = (u32*)(As + row * 64 + ko);
            *(int4*)dp = *(int4*)&p[0];
            *(int4*)(dp + 4) = *(int4*)&p[4];
        }
        __syncthreads();   // drains async vmcnt + ds writes

        #pragma unroll
        for (int kk = 0; kk < 2; ++kk) {
            bf16x8 af[RT], bfv[CT];
            #pragma unroll
            for (int rt = 0; rt < RT; ++rt) {
                int row = wrow * 64 + rt * 16 + lm;
                af[rt] = *(const bf16x8*)(As + row * 64 + kk * 32 + quad * 8);
            }
            #pragma unroll
            for (int ct = 0; ct < CT; ++ct) {
                int n = wcol * CT * 16 + ct * 16 + lm;
                bfv[ct] = *(const bf16x8*)(Bs + n * 64 + kk * 32 + quad * 8);
            }
            #pragma unroll
            for (int rt = 0; rt < RT; ++rt)
                #pragma unroll
                for (int ct = 0; ct < CT; ++ct)
                    acc[rt][ct] = __builtin_amdgcn_mfma_f32_16x16x32_bf16(
                        af[rt], bfv[ct], acc[rt][ct], 0, 0, 0);
        }
        __syncthreads();   // before next stage overwrites LDS
    }

    // epilogue: acc -> LDS C-tile [MT][NT] bf16, then coalesced 16B stores
    #pragma unroll
    for (int rt = 0; rt < RT; ++rt)
        #pragma unroll
        for (int ct = 0; ct < CT; ++ct) {
            int col = wcol * CT * 16 + ct * 16 + lm;
            #pragma unroll
            for (int r = 0; r < 4; ++r) {
                int row = wrow * 64 + rt * 16 + quad * 4 + r;  // C/D: row=quad*4+reg, col=lane&15
                lds[row * NT + col] = f2bf(acc[rt][ct][r]);
            }
        }
    __syncthreads();
    constexpr int NC = MT * NT / 2048;
    #pragma unroll
    for (int i = 0; i < NC; ++i) {
        int c = i * 256 + tid;
        int row = (c * 8) / NT;
        if (m0 + row < M)
            *(int4*)(C + (size_t)m0 * NT + c * 8) = *(const int4*)(lds + c * 8);
    }
}

// ---------------- SpMM1 + bias + ReLU (one wave/node, 4 feats/lane) ----------------

__global__ __launch_bounds__(256) void spmm_bias_relu_kernel(
    const u16* __restrict__ S, const int* __restrict__ rowstart,
    const int2* __restrict__ csr, const float* __restrict__ bias,
    u16* __restrict__ H, int n) {
    int node = blockIdx.x * 4 + (threadIdx.x >> 6);
    if (node >= n) return;
    int lane = threadIdx.x & 63;
    int beg = rowstart[node], end = rowstart[node + 1];
    float a0 = 0.f, a1 = 0.f, a2 = 0.f, a3 = 0.f;
    int j = beg;
    for (; j + 4 <= end; j += 4) {           // 4 outstanding gathers
        int2 e0 = csr[j], e1 = csr[j + 1], e2 = csr[j + 2], e3 = csr[j + 3];
        ushort4 v0 = *(const ushort4*)(S + (size_t)e0.x * NHID + lane * 4);
        ushort4 v1 = *(const ushort4*)(S + (size_t)e1.x * NHID + lane * 4);
        ushort4 v2 = *(const ushort4*)(S + (size_t)e2.x * NHID + lane * 4);
        ushort4 v3 = *(const ushort4*)(S + (size_t)e3.x * NHID + lane * 4);
        float w0 = __int_as_float(e0.y), w1 = __int_as_float(e1.y);
        float w2 = __int_as_float(e2.y), w3 = __int_as_float(e3.y);
        a0 += w0 * bf2f(v0.x) + w1 * bf2f(v1.x) + w2 * bf2f(v2.x) + w3 * bf2f(v3.x);
        a1 += w0 * bf2f(v0.y) + w1 * bf2f(v1.y) + w2 * bf2f(v2.y) + w3 * bf2f(v3.y);
        a2 += w0 * bf2f(v0.z) + w1 * bf2f(v1.z) + w2 * bf2f(v2.z) + w3 * bf2f(v3.z);
        a3 += w0 * bf2f(v0.w) + w1 * bf2f(v1.w) + w2 * bf2f(v2.w) + w3 * bf2f(v3.w);
    }
    for (; j < end; ++j) {
        int2 e0 = csr[j];
        float w0 = __int_as_float(e0.y);
        ushort4 v0 = *(const ushort4*)(S + (size_t)e0.x * NHID + lane * 4);
        a0 += w0 * bf2f(v0.x); a1 += w0 * bf2f(v0.y);
        a2 += w0 * bf2f(v0.z); a3 += w0 * bf2f(v0.w);
    }
    float4 bv = *(const float4*)(bias + lane * 4);
    a0 = fmaxf(a0 + bv.x, 0.f);
    a1 = fmaxf(a1 + bv.y, 0.f);
    a2 = fmaxf(a2 + bv.z, 0.f);
    a3 = fmaxf(a3 + bv.w, 0.f);
    ushort4 o;
    o.x = f2bf(a0); o.y = f2bf(a1); o.z = f2bf(a2); o.w = f2bf(a3);
    *(ushort4*)(H + (size_t)node * NHID + lane * 4) = o;
}

// ---------------- SpMM2 + bias + log_softmax (one wave/node, 1 class/lane) ----------------

__global__ __launch_bounds__(256) void spmm_bias_lsm_kernel(
    const u16* __restrict__ S, const int* __restrict__ rowstart,
    const int2* __restrict__ csr, const float* __restrict__ bias,
    float* __restrict__ out, int n) {
    int node = blockIdx.x * 4 + (threadIdx.x >> 6);
    if (node >= n) return;
    int lane = threadIdx.x & 63;
    int beg = rowstart[node], end = rowstart[node + 1];
    float acc = 0.f;
    int j = beg;
    for (; j + 4 <= end; j += 4) {
        int2 e0 = csr[j], e1 = csr[j + 1], e2 = csr[j + 2], e3 = csr[j + 3];
        float v0 = bf2f(S[(size_t)e0.x * NCLASS + lane]);
        float v1 = bf2f(S[(size_t)e1.x * NCLASS + lane]);
        float v2 = bf2f(S[(size_t)e2.x * NCLASS + lane]);
        float v3 = bf2f(S[(size_t)e3.x * NCLASS + lane]);
        acc += __int_as_float(e0.y) * v0 + __int_as_float(e1.y) * v1
             + __int_as_float(e2.y) * v2 + __int_as_float(e3.y) * v3;
    }
    for (; j < end; ++j)
        acc += __int_as_float(csr[j].y) * bf2f(S[(size_t)csr[j].x * NCLASS + lane]);

    float x = acc + bias[lane];
    float m = x;
    #pragma unroll
    for (int off = 32; off > 0; off >>= 1) m = fmaxf(m, __shfl_xor(m, off));
    float e = expf(x - m);
    float ssum = e;
    #pragma unroll
    for (int off = 32; off > 0; off >>= 1) ssum += __shfl_xor(ssum, off);
    out[(size_t)node * NCLASS + lane] = x - m - logf(ssum);
}

// ---------------- launch ----------------

extern "C" void kernel_launch(void* const* d_in, const int* in_sizes, int n_in,
                              void* d_out, int out_size, void* d_ws, size_t ws_size,
                              hipStream_t stream) {
    const float* x  = (const float*)d_in[0];   // [50000,512]
    const float* W1 = (const float*)d_in[1];   // [512,256]
    const float* b1 = (const float*)d_in[2];   // [256]
    const float* W2 = (const float*)d_in[3];   // [256,64]
    const float* b2 = (const float*)d_in[4];   // [64]
    const float* ew = (const float*)d_in[5];   // [800000]
    const int* esrc = (const int*)d_in[6];
    const int* edst = (const int*)d_in[7];
    float* out = (float*)d_out;                // [50000,64]

    char* ws = (char*)d_ws;
    size_t off = 0;
    auto take = [&](size_t bytes) -> void* {
        off = (off + 255) & ~(size_t)255;
        void* p = ws + off;
        off += bytes;
        return p;
    };
    u16*  S1       = (u16*) take((size_t)N_NODES * NHID * 2);    // 25.6 MB
    u16*  H        = (u16*) take((size_t)N_NODES * NHID * 2);    // 25.6 MB
    u16*  S2       = (u16*) take((size_t)N_NODES * NCLASS * 2);  // 6.4 MB
    u16*  W1T      = (u16*) take((size_t)NHID * NFEAT * 2);      // [256][512]
    u16*  W2T      = (u16*) take((size_t)NCLASS * NHID * 2);     // [64][256]
    int*  deg      = (int*) take((size_t)DEG_PAD * 4);
    int*  rowstart = (int*) take((size_t)(N_NODES + 1) * 4);
    int*  fill     = (int*) take((size_t)N_NODES * 4);
    int2* csr      = (int2*)take((size_t)N_EDGES * 8);
    (void)ws_size; (void)in_sizes; (void)n_in; (void)out_size;

    // weight prep
    transpose_cvt<<<(NFEAT * NHID + 255) / 256, 256, 0, stream>>>(W1, W1T, NFEAT, NHID);
    transpose_cvt<<<(NHID * NCLASS + 255) / 256, 256, 0, stream>>>(W2, W2T, NHID, NCLASS);

    // CSR build
    hipMemsetAsync(deg, 0, (size_t)DEG_PAD * 4, stream);
    count_kernel<<<(N_EDGES + 255) / 256, 256, 0, stream>>>(edst, deg, N_EDGES);
    scan_kernel<<<1, 1024, 0, stream>>>(deg, rowstart, fill, N_NODES);
    scatter_kernel<<<(N_EDGES + 255) / 256, 256, 0, stream>>>(esrc, edst, ew, fill, csr, N_EDGES);

    // layer 1
    gemm_bt<64, 256, 4, false, NFEAT><<<(N_NODES + 63) / 64, 256, 0, stream>>>(
        (const void*)x, W1T, S1, N_NODES);
    spmm_bias_relu_kernel<<<(N_NODES + 3) / 4, 256, 0, stream>>>(
        S1, rowstart, csr, b1, H, N_NODES);

    // layer 2
    gemm_bt<128, 64, 2, true, NHID><<<(N_NODES + 127) / 128, 256, 0, stream>>>(
        (const void*)H, W2T, S2, N_NODES);
    spmm_bias_lsm_kernel<<<(N_NODES + 3) / 4, 256, 0, stream>>>(
        S2, rowstart, csr, b2, out, N_NODES);
}

// Round 5
// 396.170 us; speedup vs baseline: 1.2214x; 1.0658x over previous
//
#include <hip/hip_runtime.h>
#include <cstdint>

// GCN forward on MI355X (gfx950). f32 in/out; bf16 MFMA GEMMs with fp32 accum;
// bf16 intermediates; 4-byte packed CSR entries (src:u16 | weight:bf16).
// Dispatch chain (7): memset deg -> prep(transposes+count) -> scan
//   -> [gemm1 || scatter] -> spmm1+bias+relu -> gemm2 -> spmm2+bias+log_softmax.

typedef unsigned short u16;
typedef unsigned int u32;
typedef __attribute__((ext_vector_type(8))) short bf16x8;
typedef __attribute__((ext_vector_type(4))) float f32x4;

#define N_NODES 50000
#define N_EDGES 800000
#define NFEAT 512
#define NHID 256
#define NCLASS 64
#define DEG_PAD 65536     // scan reads unguarded int4; zero-padded

#define GB1 782           // gemm1 blocks: ceil(50000/64)
#define SB  391           // scatter blocks: ceil(800000/2048)

__device__ __forceinline__ float bf2f(u16 h) {
    union { u32 u; float f; } c; c.u = ((u32)h) << 16; return c.f;
}
__device__ __forceinline__ u16 f2bf(float f) {
    union { float f; u32 u; } c; c.f = f;
    u32 u = c.u;
    return (u16)((u + 0x7fffu + ((u >> 16) & 1u)) >> 16);   // RNE
}
__device__ __forceinline__ u32 pk2(float a, float b) {
    return (u32)f2bf(a) | ((u32)f2bf(b) << 16);
}

// async global->LDS, 16B per lane; LDS dest = wave-uniform base + lane*16.
__device__ __forceinline__ void async16(const void* g, void* l) {
    __builtin_amdgcn_global_load_lds(
        (const __attribute__((address_space(1))) void*)(uintptr_t)g,
        (__attribute__((address_space(3))) void*)(uintptr_t)l, 16, 0, 0);
}

// ---------------- prep: W1/W2 transpose+cvt + degree count (fused) ----------------
// blocks [0,512): W1T, [512,576): W2T, [576,1358): count (4 edges/thread)

__global__ __launch_bounds__(256) void prep_kernel(
    const float* __restrict__ W1, u16* __restrict__ W1T,
    const float* __restrict__ W2, u16* __restrict__ W2T,
    const int* __restrict__ edst, int* __restrict__ deg) {
    int b = blockIdx.x;
    if (b < 512) {
        int idx = b * 256 + threadIdx.x;           // W1T[256][512]
        int n = idx >> 9, k = idx & 511;
        W1T[idx] = f2bf(W1[(size_t)k * NHID + n]);
    } else if (b < 576) {
        int idx = (b - 512) * 256 + threadIdx.x;   // W2T[64][256]
        int n = idx >> 8, k = idx & 255;
        W2T[idx] = f2bf(W2[(size_t)k * NCLASS + n]);
    } else {
        int base = (b - 576) * 1024 + threadIdx.x;
        #pragma unroll
        for (int i = 0; i < 4; ++i) {
            int e = base + i * 256;
            if (e < N_EDGES) atomicAdd(&deg[edst[e]], 1);
        }
    }
}

// ---------------- scan: deg[0..n) -> rowstart[0..n], fill[i]=rowstart[i] ----------------

__global__ __launch_bounds__(1024) void scan_kernel(const int* __restrict__ deg,
                                                    int* __restrict__ rowstart,
                                                    int* __restrict__ fill, int n) {
    __shared__ int wsum[16];
    __shared__ int s_carry;
    const int tid = threadIdx.x;
    const int lane = tid & 63, wid = tid >> 6;
    if (tid == 0) s_carry = 0;
    __syncthreads();
    const int CH = 16;
    for (int base = 0; base < DEG_PAD; base += 1024 * CH) {   // 4 iterations
        int i0 = base + tid * CH;
        int v[CH];
        #pragma unroll
        for (int q = 0; q < 4; ++q)
            *(int4*)&v[q * 4] = *(const int4*)(deg + i0 + q * 4);
        int s = 0;
        #pragma unroll
        for (int j = 0; j < CH; ++j) s += v[j];
        int incl = s;
        #pragma unroll
        for (int off = 1; off < 64; off <<= 1) {
            int t = __shfl_up(incl, off);
            if (lane >= off) incl += t;
        }
        if (lane == 63) wsum[wid] = incl;
        __syncthreads();
        if (wid == 0) {
            int ws = (lane < 16) ? wsum[lane] : 0;
            #pragma unroll
            for (int off = 1; off < 16; off <<= 1) {
                int t = __shfl_up(ws, off);
                if (lane >= off) ws += t;
            }
            if (lane < 16) wsum[lane] = ws;
        }
        __syncthreads();
        int carry = s_carry + ((wid > 0) ? wsum[wid - 1] : 0);
        int pre = carry + incl - s;   // exclusive prefix for this thread's chunk
        #pragma unroll
        for (int j = 0; j < CH; ++j) {
            int i = i0 + j;
            if (i < n) { rowstart[i] = pre; fill[i] = pre; }
            pre += v[j];
        }
        __syncthreads();
        if (tid == 1023) s_carry = carry + incl;   // wave-15 inclusive total
        __syncthreads();
    }
    if (tid == 0) rowstart[n] = s_carry;
}

// ---------------- shared GEMM body: C[M,NT] = A[M,K] @ BT[NT][K]^T ----------------
// 4 waves WROWSxWCOLS; BK=64 (2 k-halves); B (and bf16 A) via global_load_lds x4;
// f32 A (MT==64 only) via load+cvt+ds_write. Epilogue repacks C tile through LDS.

template <int MT, int NT, int WCOLS, bool A_BF16, int K>
__device__ __forceinline__ void gemm_body(const void* __restrict__ Aptr,
                                          const u16* __restrict__ BT,
                                          u16* __restrict__ C, int M,
                                          int bid, u16* lds) {
    constexpr int WROWS = 4 / WCOLS;
    constexpr int RT = MT / (16 * WROWS);
    constexpr int CT = NT / (16 * WCOLS);
    u16* As = lds;             // [MT][64] contiguous
    u16* Bs = lds + MT * 64;   // [NT][64] contiguous (B^T: row n, k-contig)

    const int tid  = threadIdx.x;
    const int wv   = tid >> 6, lane = tid & 63;
    const int lm   = lane & 15, quad = lane >> 4;
    const int wrow = wv / WCOLS, wcol = wv % WCOLS;
    const int m0   = bid * MT;

    f32x4 acc[RT][CT];
    #pragma unroll
    for (int r = 0; r < RT; ++r)
        #pragma unroll
        for (int c = 0; c < CT; ++c) acc[r][c] = (f32x4){0.f, 0.f, 0.f, 0.f};

    for (int k0 = 0; k0 < K; k0 += 64) {
        #pragma unroll
        for (int i = 0; i < NT / 32; ++i) {
            int c = i * 256 + tid;
            int n = c >> 3, ko = (c & 7) * 8;
            async16(BT + (size_t)n * K + k0 + ko, Bs + c * 8);
        }
        if (A_BF16) {
            #pragma unroll
            for (int i = 0; i < MT / 32; ++i) {
                int c = i * 256 + tid;
                int row = c >> 3, ko = (c & 7) * 8;
                int gr = m0 + row; if (gr > M - 1) gr = M - 1;
                async16((const u16*)Aptr + (size_t)gr * K + k0 + ko, As + c * 8);
            }
        } else {
            int row = tid >> 2, ko = (tid & 3) * 16;   // MT==64 path
            int gr = m0 + row; if (gr > M - 1) gr = M - 1;
            const float4* gp = (const float4*)((const float*)Aptr + (size_t)gr * K + k0 + ko);
            float4 f0 = gp[0], f1 = gp[1], f2 = gp[2], f3 = gp[3];
            u32 p[8] = {pk2(f0.x, f0.y), pk2(f0.z, f0.w), pk2(f1.x, f1.y), pk2(f1.z, f1.w),
                        pk2(f2.x, f2.y), pk2(f2.z, f2.w), pk2(f3.x, f3.y), pk2(f3.z, f3.w)};
            u32* dp = (u32*)(As + row * 64 + ko);
            *(int4*)dp = *(int4*)&p[0];
            *(int4*)(dp + 4) = *(int4*)&p[4];
        }
        __syncthreads();

        #pragma unroll
        for (int kk = 0; kk < 2; ++kk) {
            bf16x8 af[RT], bfv[CT];
            #pragma unroll
            for (int rt = 0; rt < RT; ++rt) {
                int row = wrow * (RT * 16) + rt * 16 + lm;
                af[rt] = *(const bf16x8*)(As + row * 64 + kk * 32 + quad * 8);
            }
            #pragma unroll
            for (int ct = 0; ct < CT; ++ct) {
                int n = wcol * CT * 16 + ct * 16 + lm;
                bfv[ct] = *(const bf16x8*)(Bs + n * 64 + kk * 32 + quad * 8);
            }
            #pragma unroll
            for (int rt = 0; rt < RT; ++rt)
                #pragma unroll
                for (int ct = 0; ct < CT; ++ct)
                    acc[rt][ct] = __builtin_amdgcn_mfma_f32_16x16x32_bf16(
                        af[rt], bfv[ct], acc[rt][ct], 0, 0, 0);
        }
        __syncthreads();
    }

    #pragma unroll
    for (int rt = 0; rt < RT; ++rt)
        #pragma unroll
        for (int ct = 0; ct < CT; ++ct) {
            int col = wcol * CT * 16 + ct * 16 + lm;
            #pragma unroll
            for (int r = 0; r < 4; ++r) {
                int row = wrow * (RT * 16) + rt * 16 + quad * 4 + r;  // C/D: row=quad*4+reg
                lds[row * NT + col] = f2bf(acc[rt][ct][r]);
            }
        }
    __syncthreads();
    constexpr int NC = MT * NT / 2048;
    #pragma unroll
    for (int i = 0; i < NC; ++i) {
        int c = i * 256 + tid;
        int row = (c * 8) / NT;
        if (m0 + row < M)
            *(int4*)(C + (size_t)m0 * NT + c * 8) = *(const int4*)(lds + c * 8);
    }
}

// ---------------- fused gemm1 || scatter ----------------
// blocks [0,GB1): gemm1 (x f32 -> S1). blocks [GB1,GB1+SB): CSR scatter (2048 edges/block).

__global__ __launch_bounds__(256) void gemm1_scatter_kernel(
    const float* __restrict__ x, const u16* __restrict__ W1T, u16* __restrict__ S1,
    const int* __restrict__ esrc, const int* __restrict__ edst,
    const float* __restrict__ ew, int* __restrict__ fill, u32* __restrict__ csr) {
    __shared__ __align__(16) u16 lds[(64 + 256) * 64];
    int b = blockIdx.x;
    if (b < GB1) {
        gemm_body<64, 256, 4, false, NFEAT>((const void*)x, W1T, S1, N_NODES, b, lds);
    } else {
        int base = (b - GB1) * 2048 + threadIdx.x;
        #pragma unroll
        for (int i = 0; i < 8; ++i) {
            int e = base + i * 256;
            if (e < N_EDGES) {
                int d = edst[e];
                int p = atomicAdd(&fill[d], 1);
                u32 pk = (u32)esrc[e] | ((u32)f2bf(ew[e]) << 16);
                __builtin_nontemporal_store(pk, csr + p);
            }
        }
    }
}

// ---------------- gemm2 standalone ----------------

__global__ __launch_bounds__(256) void gemm2_kernel(const u16* __restrict__ H,
                                                    const u16* __restrict__ W2T,
                                                    u16* __restrict__ S2, int M) {
    __shared__ __align__(16) u16 lds[(128 + 64) * 64];
    gemm_body<128, 64, 2, true, NHID>((const void*)H, W2T, S2, M, blockIdx.x, lds);
}

// ---------------- SpMM1 + bias + ReLU (one wave/node, 4 feats/lane, 8-way unroll) ----------------

__global__ __launch_bounds__(256) void spmm_bias_relu_kernel(
    const u16* __restrict__ S, const int* __restrict__ rowstart,
    const u32* __restrict__ csr, const float* __restrict__ bias,
    u16* __restrict__ H, int n) {
    int node = blockIdx.x * 4 + (threadIdx.x >> 6);
    if (node >= n) return;
    int lane = threadIdx.x & 63;
    int beg = rowstart[node], end = rowstart[node + 1];
    float a0 = 0.f, a1 = 0.f, a2 = 0.f, a3 = 0.f;
    int j = beg;
    for (; j + 8 <= end; j += 8) {           // 8 outstanding gathers
        u32 e[8];
        #pragma unroll
        for (int i = 0; i < 8; ++i) e[i] = csr[j + i];   // uniform: s_load_dwordx8
        ushort4 v[8];
        #pragma unroll
        for (int i = 0; i < 8; ++i)
            v[i] = *(const ushort4*)(S + (size_t)(e[i] & 0xFFFFu) * NHID + lane * 4);
        #pragma unroll
        for (int i = 0; i < 8; ++i) {
            float w = bf2f((u16)(e[i] >> 16));
            a0 += w * bf2f(v[i].x); a1 += w * bf2f(v[i].y);
            a2 += w * bf2f(v[i].z); a3 += w * bf2f(v[i].w);
        }
    }
    for (; j < end; ++j) {
        u32 e0 = csr[j];
        float w = bf2f((u16)(e0 >> 16));
        ushort4 v0 = *(const ushort4*)(S + (size_t)(e0 & 0xFFFFu) * NHID + lane * 4);
        a0 += w * bf2f(v0.x); a1 += w * bf2f(v0.y);
        a2 += w * bf2f(v0.z); a3 += w * bf2f(v0.w);
    }
    float4 bv = *(const float4*)(bias + lane * 4);
    a0 = fmaxf(a0 + bv.x, 0.f);
    a1 = fmaxf(a1 + bv.y, 0.f);
    a2 = fmaxf(a2 + bv.z, 0.f);
    a3 = fmaxf(a3 + bv.w, 0.f);
    ushort4 o;
    o.x = f2bf(a0); o.y = f2bf(a1); o.z = f2bf(a2); o.w = f2bf(a3);
    *(ushort4*)(H + (size_t)node * NHID + lane * 4) = o;
}

// ---------------- SpMM2 + bias + log_softmax (one wave/node, 1 class/lane, 8-way) ----------------

__global__ __launch_bounds__(256) void spmm_bias_lsm_kernel(
    const u16* __restrict__ S, const int* __restrict__ rowstart,
    const u32* __restrict__ csr, const float* __restrict__ bias,
    float* __restrict__ out, int n) {
    int node = blockIdx.x * 4 + (threadIdx.x >> 6);
    if (node >= n) return;
    int lane = threadIdx.x & 63;
    int beg = rowstart[node], end = rowstart[node + 1];
    float acc = 0.f;
    int j = beg;
    for (; j + 8 <= end; j += 8) {
        u32 e[8];
        #pragma unroll
        for (int i = 0; i < 8; ++i) e[i] = csr[j + i];
        u16 v[8];
        #pragma unroll
        for (int i = 0; i < 8; ++i)
            v[i] = S[(size_t)(e[i] & 0xFFFFu) * NCLASS + lane];
        #pragma unroll
        for (int i = 0; i < 8; ++i)
            acc += bf2f((u16)(e[i] >> 16)) * bf2f(v[i]);
    }
    for (; j < end; ++j) {
        u32 e0 = csr[j];
        acc += bf2f((u16)(e0 >> 16)) * bf2f(S[(size_t)(e0 & 0xFFFFu) * NCLASS + lane]);
    }

    float x = acc + bias[lane];
    float m = x;
    #pragma unroll
    for (int off = 32; off > 0; off >>= 1) m = fmaxf(m, __shfl_xor(m, off));
    float e = expf(x - m);
    float ssum = e;
    #pragma unroll
    for (int off = 32; off > 0; off >>= 1) ssum += __shfl_xor(ssum, off);
    out[(size_t)node * NCLASS + lane] = x - m - logf(ssum);
}

// ---------------- launch ----------------

extern "C" void kernel_launch(void* const* d_in, const int* in_sizes, int n_in,
                              void* d_out, int out_size, void* d_ws, size_t ws_size,
                              hipStream_t stream) {
    const float* x  = (const float*)d_in[0];   // [50000,512]
    const float* W1 = (const float*)d_in[1];   // [512,256]
    const float* b1 = (const float*)d_in[2];   // [256]
    const float* W2 = (const float*)d_in[3];   // [256,64]
    const float* b2 = (const float*)d_in[4];   // [64]
    const float* ew = (const float*)d_in[5];   // [800000]
    const int* esrc = (const int*)d_in[6];
    const int* edst = (const int*)d_in[7];
    float* out = (float*)d_out;                // [50000,64]

    char* ws = (char*)d_ws;
    size_t off = 0;
    auto take = [&](size_t bytes) -> void* {
        off = (off + 255) & ~(size_t)255;
        void* p = ws + off;
        off += bytes;
        return p;
    };
    u16* S1       = (u16*)take((size_t)N_NODES * NHID * 2);    // 25.6 MB
    u16* H        = (u16*)take((size_t)N_NODES * NHID * 2);    // 25.6 MB
    u16* S2       = (u16*)take((size_t)N_NODES * NCLASS * 2);  // 6.4 MB
    u16* W1T      = (u16*)take((size_t)NHID * NFEAT * 2);      // [256][512]
    u16* W2T      = (u16*)take((size_t)NCLASS * NHID * 2);     // [64][256]
    int* deg      = (int*)take((size_t)DEG_PAD * 4);
    int* rowstart = (int*)take((size_t)(N_NODES + 1) * 4);
    int* fill     = (int*)take((size_t)N_NODES * 4);
    u32* csr      = (u32*)take((size_t)N_EDGES * 4);           // 3.2 MB packed
    (void)ws_size; (void)in_sizes; (void)n_in; (void)out_size;

    hipMemsetAsync(deg, 0, (size_t)DEG_PAD * 4, stream);
    prep_kernel<<<1358, 256, 0, stream>>>(W1, W1T, W2, W2T, edst, deg);
    scan_kernel<<<1, 1024, 0, stream>>>(deg, rowstart, fill, N_NODES);
    gemm1_scatter_kernel<<<GB1 + SB, 256, 0, stream>>>(x, W1T, S1, esrc, edst, ew, fill, csr);
    spmm_bias_relu_kernel<<<(N_NODES + 3) / 4, 256, 0, stream>>>(
        S1, rowstart, csr, b1, H, N_NODES);
    gemm2_kernel<<<(N_NODES + 127) / 128, 256, 0, stream>>>(H, W2T, S2, N_NODES);
    spmm_bias_lsm_kernel<<<(N_NODES + 3) / 4, 256, 0, stream>>>(
        S2, rowstart, csr, b2, out, N_NODES);
}

// Round 6
// 351.842 us; speedup vs baseline: 1.3752x; 1.1260x over previous
//
#include <hip/hip_runtime.h>
#include <cstdint>

// GCN forward on MI355X (gfx950). f32 in/out; bf16 MFMA GEMMs with fp32 accum;
// bf16 intermediates; 4-byte packed CSR entries (src:u16 | weight:bf16).
// CSR build is atomic-light: count pass records per-edge rank (atomicAdd return),
// scatter is then atomic-free: csr[rowstart[dst]+rank] = entry.
// Dispatch chain (7): memset deg -> prep(transposes+count+rank) -> scan
//   -> [gemm1 || scatter] -> spmm1+bias+relu -> gemm2 -> spmm2+bias+log_softmax.

typedef unsigned short u16;
typedef unsigned int u32;
typedef __attribute__((ext_vector_type(8))) short bf16x8;
typedef __attribute__((ext_vector_type(4))) float f32x4;

#define N_NODES 50000
#define N_EDGES 800000
#define NFEAT 512
#define NHID 256
#define NCLASS 64
#define DEG_PAD 65536     // scan reads unguarded int4; zero-padded

#define GB1 782           // gemm1 blocks: ceil(50000/64)
#define SB  391           // scatter blocks: 800000/(256*8) = 390.6 -> 391

__device__ __forceinline__ float bf2f(u16 h) {
    union { u32 u; float f; } c; c.u = ((u32)h) << 16; return c.f;
}
__device__ __forceinline__ u16 f2bf(float f) {
    union { float f; u32 u; } c; c.f = f;
    u32 u = c.u;
    return (u16)((u + 0x7fffu + ((u >> 16) & 1u)) >> 16);   // RNE
}
__device__ __forceinline__ u32 pk2(float a, float b) {
    return (u32)f2bf(a) | ((u32)f2bf(b) << 16);
}

// async global->LDS, 16B per lane; LDS dest = wave-uniform base + lane*16.
__device__ __forceinline__ void async16(const void* g, void* l) {
    __builtin_amdgcn_global_load_lds(
        (const __attribute__((address_space(1))) void*)(uintptr_t)g,
        (__attribute__((address_space(3))) void*)(uintptr_t)l, 16, 0, 0);
}

// ---------------- prep: W1/W2 transpose+cvt + degree count + rank ----------------
// blocks [0,512): W1T, [512,576): W2T, [576,967): count 8 edges/thread (int4 loads)

__global__ __launch_bounds__(256) void prep_kernel(
    const float* __restrict__ W1, u16* __restrict__ W1T,
    const float* __restrict__ W2, u16* __restrict__ W2T,
    const int* __restrict__ edst, int* __restrict__ deg, int* __restrict__ rank) {
    int b = blockIdx.x;
    if (b < 512) {
        int idx = b * 256 + threadIdx.x;           // W1T[256][512]
        int n = idx >> 9, k = idx & 511;
        W1T[idx] = f2bf(W1[(size_t)k * NHID + n]);
    } else if (b < 576) {
        int idx = (b - 512) * 256 + threadIdx.x;   // W2T[64][256]
        int n = idx >> 8, k = idx & 255;
        W2T[idx] = f2bf(W2[(size_t)k * NCLASS + n]);
    } else {
        int e0 = ((b - 576) * 256 + threadIdx.x) * 8;
        if (e0 < N_EDGES) {                        // 800000 % 8 == 0: full chunk
            int4 d0 = *(const int4*)(edst + e0);
            int4 d1 = *(const int4*)(edst + e0 + 4);
            int d[8] = {d0.x, d0.y, d0.z, d0.w, d1.x, d1.y, d1.z, d1.w};
            int r[8];
            #pragma unroll
            for (int i = 0; i < 8; ++i) r[i] = atomicAdd(&deg[d[i]], 1);
            *(int4*)(rank + e0)     = make_int4(r[0], r[1], r[2], r[3]);
            *(int4*)(rank + e0 + 4) = make_int4(r[4], r[5], r[6], r[7]);
        }
    }
}

// ---------------- scan: deg[0..n) -> rowstart[0..n] ----------------

__global__ __launch_bounds__(1024) void scan_kernel(const int* __restrict__ deg,
                                                    int* __restrict__ rowstart, int n) {
    __shared__ int wsum[16];
    __shared__ int s_carry;
    const int tid = threadIdx.x;
    const int lane = tid & 63, wid = tid >> 6;
    if (tid == 0) s_carry = 0;
    __syncthreads();
    const int CH = 16;
    for (int base = 0; base < DEG_PAD; base += 1024 * CH) {   // 4 iterations
        int i0 = base + tid * CH;
        int v[CH];
        #pragma unroll
        for (int q = 0; q < 4; ++q)
            *(int4*)&v[q * 4] = *(const int4*)(deg + i0 + q * 4);
        int s = 0;
        #pragma unroll
        for (int j = 0; j < CH; ++j) s += v[j];
        int incl = s;
        #pragma unroll
        for (int off = 1; off < 64; off <<= 1) {
            int t = __shfl_up(incl, off);
            if (lane >= off) incl += t;
        }
        if (lane == 63) wsum[wid] = incl;
        __syncthreads();
        if (wid == 0) {
            int ws = (lane < 16) ? wsum[lane] : 0;
            #pragma unroll
            for (int off = 1; off < 16; off <<= 1) {
                int t = __shfl_up(ws, off);
                if (lane >= off) ws += t;
            }
            if (lane < 16) wsum[lane] = ws;
        }
        __syncthreads();
        int carry = s_carry + ((wid > 0) ? wsum[wid - 1] : 0);
        int pre = carry + incl - s;   // exclusive prefix for this thread's chunk
        #pragma unroll
        for (int j = 0; j < CH; ++j) {
            int i = i0 + j;
            if (i < n) rowstart[i] = pre;
            pre += v[j];
        }
        __syncthreads();
        if (tid == 1023) s_carry = carry + incl;   // wave-15 inclusive total
        __syncthreads();
    }
    if (tid == 0) rowstart[n] = s_carry;
}

// ---------------- shared GEMM body: C[M,NT] = A[M,K] @ BT[NT][K]^T ----------------

template <int MT, int NT, int WCOLS, bool A_BF16, int K>
__device__ __forceinline__ void gemm_body(const void* __restrict__ Aptr,
                                          const u16* __restrict__ BT,
                                          u16* __restrict__ C, int M,
                                          int bid, u16* lds) {
    constexpr int WROWS = 4 / WCOLS;
    constexpr int RT = MT / (16 * WROWS);
    constexpr int CT = NT / (16 * WCOLS);
    u16* As = lds;             // [MT][64] contiguous
    u16* Bs = lds + MT * 64;   // [NT][64] contiguous (B^T: row n, k-contig)

    const int tid  = threadIdx.x;
    const int wv   = tid >> 6, lane = tid & 63;
    const int lm   = lane & 15, quad = lane >> 4;
    const int wrow = wv / WCOLS, wcol = wv % WCOLS;
    const int m0   = bid * MT;

    f32x4 acc[RT][CT];
    #pragma unroll
    for (int r = 0; r < RT; ++r)
        #pragma unroll
        for (int c = 0; c < CT; ++c) acc[r][c] = (f32x4){0.f, 0.f, 0.f, 0.f};

    for (int k0 = 0; k0 < K; k0 += 64) {
        #pragma unroll
        for (int i = 0; i < NT / 32; ++i) {
            int c = i * 256 + tid;
            int n = c >> 3, ko = (c & 7) * 8;
            async16(BT + (size_t)n * K + k0 + ko, Bs + c * 8);
        }
        if (A_BF16) {
            #pragma unroll
            for (int i = 0; i < MT / 32; ++i) {
                int c = i * 256 + tid;
                int row = c >> 3, ko = (c & 7) * 8;
                int gr = m0 + row; if (gr > M - 1) gr = M - 1;
                async16((const u16*)Aptr + (size_t)gr * K + k0 + ko, As + c * 8);
            }
        } else {
            int row = tid >> 2, ko = (tid & 3) * 16;   // MT==64 path
            int gr = m0 + row; if (gr > M - 1) gr = M - 1;
            const float4* gp = (const float4*)((const float*)Aptr + (size_t)gr * K + k0 + ko);
            float4 f0 = gp[0], f1 = gp[1], f2 = gp[2], f3 = gp[3];
            u32 p[8] = {pk2(f0.x, f0.y), pk2(f0.z, f0.w), pk2(f1.x, f1.y), pk2(f1.z, f1.w),
                        pk2(f2.x, f2.y), pk2(f2.z, f2.w), pk2(f3.x, f3.y), pk2(f3.z, f3.w)};
            u32* dp = (u32*)(As + row * 64 + ko);
            *(int4*)dp = *(int4*)&p[0];
            *(int4*)(dp + 4) = *(int4*)&p[4];
        }
        __syncthreads();

        #pragma unroll
        for (int kk = 0; kk < 2; ++kk) {
            bf16x8 af[RT], bfv[CT];
            #pragma unroll
            for (int rt = 0; rt < RT; ++rt) {
                int row = wrow * (RT * 16) + rt * 16 + lm;
                af[rt] = *(const bf16x8*)(As + row * 64 + kk * 32 + quad * 8);
            }
            #pragma unroll
            for (int ct = 0; ct < CT; ++ct) {
                int n = wcol * CT * 16 + ct * 16 + lm;
                bfv[ct] = *(const bf16x8*)(Bs + n * 64 + kk * 32 + quad * 8);
            }
            #pragma unroll
            for (int rt = 0; rt < RT; ++rt)
                #pragma unroll
                for (int ct = 0; ct < CT; ++ct)
                    acc[rt][ct] = __builtin_amdgcn_mfma_f32_16x16x32_bf16(
                        af[rt], bfv[ct], acc[rt][ct], 0, 0, 0);
        }
        __syncthreads();
    }

    #pragma unroll
    for (int rt = 0; rt < RT; ++rt)
        #pragma unroll
        for (int ct = 0; ct < CT; ++ct) {
            int col = wcol * CT * 16 + ct * 16 + lm;
            #pragma unroll
            for (int r = 0; r < 4; ++r) {
                int row = wrow * (RT * 16) + rt * 16 + quad * 4 + r;  // C/D: row=quad*4+reg
                lds[row * NT + col] = f2bf(acc[rt][ct][r]);
            }
        }
    __syncthreads();
    constexpr int NC = MT * NT / 2048;
    #pragma unroll
    for (int i = 0; i < NC; ++i) {
        int c = i * 256 + tid;
        int row = (c * 8) / NT;
        if (m0 + row < M)
            *(int4*)(C + (size_t)m0 * NT + c * 8) = *(const int4*)(lds + c * 8);
    }
}

// ---------------- fused gemm1 || scatter ----------------
// blocks [0,GB1): gemm1 (x f32 -> S1). blocks [GB1,GB1+SB): atomic-free CSR scatter,
// 8 contiguous edges/thread via int4 loads; position = rowstart[dst] + rank.

__global__ __launch_bounds__(256) void gemm1_scatter_kernel(
    const float* __restrict__ x, const u16* __restrict__ W1T, u16* __restrict__ S1,
    const int* __restrict__ esrc, const int* __restrict__ edst,
    const float* __restrict__ ew, const int* __restrict__ rowstart,
    const int* __restrict__ rank, u32* __restrict__ csr) {
    __shared__ __align__(16) u16 lds[(64 + 256) * 64];
    int b = blockIdx.x;
    if (b < GB1) {
        gemm_body<64, 256, 4, false, NFEAT>((const void*)x, W1T, S1, N_NODES, b, lds);
    } else {
        int e0 = ((b - GB1) * 256 + threadIdx.x) * 8;
        if (e0 < N_EDGES) {                       // 800000 % 8 == 0: full chunk
            int4 d0 = *(const int4*)(edst + e0),  d1 = *(const int4*)(edst + e0 + 4);
            int4 s0 = *(const int4*)(esrc + e0),  s1 = *(const int4*)(esrc + e0 + 4);
            float4 w0 = *(const float4*)(ew + e0), w1 = *(const float4*)(ew + e0 + 4);
            int4 r0 = *(const int4*)(rank + e0),  r1 = *(const int4*)(rank + e0 + 4);
            int d[8] = {d0.x, d0.y, d0.z, d0.w, d1.x, d1.y, d1.z, d1.w};
            int s[8] = {s0.x, s0.y, s0.z, s0.w, s1.x, s1.y, s1.z, s1.w};
            float w[8] = {w0.x, w0.y, w0.z, w0.w, w1.x, w1.y, w1.z, w1.w};
            int r[8] = {r0.x, r0.y, r0.z, r0.w, r1.x, r1.y, r1.z, r1.w};
            #pragma unroll
            for (int i = 0; i < 8; ++i) {
                int p = rowstart[d[i]] + r[i];
                csr[p] = (u32)s[i] | ((u32)f2bf(w[i]) << 16);   // cached store: L2-merge
            }
        }
    }
}

// ---------------- gemm2 standalone ----------------

__global__ __launch_bounds__(256) void gemm2_kernel(const u16* __restrict__ H,
                                                    const u16* __restrict__ W2T,
                                                    u16* __restrict__ S2, int M) {
    __shared__ __align__(16) u16 lds[(128 + 64) * 64];
    gemm_body<128, 64, 2, true, NHID>((const void*)H, W2T, S2, M, blockIdx.x, lds);
}

// ---------------- SpMM1 + bias + ReLU (one wave/node, 4 feats/lane, 8-way unroll) ----------------

__global__ __launch_bounds__(256) void spmm_bias_relu_kernel(
    const u16* __restrict__ S, const int* __restrict__ rowstart,
    const u32* __restrict__ csr, const float* __restrict__ bias,
    u16* __restrict__ H, int n) {
    int node = blockIdx.x * 4 + (threadIdx.x >> 6);
    if (node >= n) return;
    int lane = threadIdx.x & 63;
    int beg = rowstart[node], end = rowstart[node + 1];
    float a0 = 0.f, a1 = 0.f, a2 = 0.f, a3 = 0.f;
    int j = beg;
    for (; j + 8 <= end; j += 8) {           // 8 outstanding gathers
        u32 e[8];
        #pragma unroll
        for (int i = 0; i < 8; ++i) e[i] = csr[j + i];   // uniform addr: s_load path
        ushort4 v[8];
        #pragma unroll
        for (int i = 0; i < 8; ++i)
            v[i] = *(const ushort4*)(S + (size_t)(e[i] & 0xFFFFu) * NHID + lane * 4);
        #pragma unroll
        for (int i = 0; i < 8; ++i) {
            float w = bf2f((u16)(e[i] >> 16));
            a0 += w * bf2f(v[i].x); a1 += w * bf2f(v[i].y);
            a2 += w * bf2f(v[i].z); a3 += w * bf2f(v[i].w);
        }
    }
    for (; j < end; ++j) {
        u32 e0 = csr[j];
        float w = bf2f((u16)(e0 >> 16));
        ushort4 v0 = *(const ushort4*)(S + (size_t)(e0 & 0xFFFFu) * NHID + lane * 4);
        a0 += w * bf2f(v0.x); a1 += w * bf2f(v0.y);
        a2 += w * bf2f(v0.z); a3 += w * bf2f(v0.w);
    }
    float4 bv = *(const float4*)(bias + lane * 4);
    a0 = fmaxf(a0 + bv.x, 0.f);
    a1 = fmaxf(a1 + bv.y, 0.f);
    a2 = fmaxf(a2 + bv.z, 0.f);
    a3 = fmaxf(a3 + bv.w, 0.f);
    ushort4 o;
    o.x = f2bf(a0); o.y = f2bf(a1); o.z = f2bf(a2); o.w = f2bf(a3);
    *(ushort4*)(H + (size_t)node * NHID + lane * 4) = o;
}

// ---------------- SpMM2 + bias + log_softmax (one wave/node, 1 class/lane, 8-way) ----------------

__global__ __launch_bounds__(256) void spmm_bias_lsm_kernel(
    const u16* __restrict__ S, const int* __restrict__ rowstart,
    const u32* __restrict__ csr, const float* __restrict__ bias,
    float* __restrict__ out, int n) {
    int node = blockIdx.x * 4 + (threadIdx.x >> 6);
    if (node >= n) return;
    int lane = threadIdx.x & 63;
    int beg = rowstart[node], end = rowstart[node + 1];
    float acc = 0.f;
    int j = beg;
    for (; j + 8 <= end; j += 8) {
        u32 e[8];
        #pragma unroll
        for (int i = 0; i < 8; ++i) e[i] = csr[j + i];
        u16 v[8];
        #pragma unroll
        for (int i = 0; i < 8; ++i)
            v[i] = S[(size_t)(e[i] & 0xFFFFu) * NCLASS + lane];
        #pragma unroll
        for (int i = 0; i < 8; ++i)
            acc += bf2f((u16)(e[i] >> 16)) * bf2f(v[i]);
    }
    for (; j < end; ++j) {
        u32 e0 = csr[j];
        acc += bf2f((u16)(e0 >> 16)) * bf2f(S[(size_t)(e0 & 0xFFFFu) * NCLASS + lane]);
    }

    float x = acc + bias[lane];
    float m = x;
    #pragma unroll
    for (int off = 32; off > 0; off >>= 1) m = fmaxf(m, __shfl_xor(m, off));
    float e = expf(x - m);
    float ssum = e;
    #pragma unroll
    for (int off = 32; off > 0; off >>= 1) ssum += __shfl_xor(ssum, off);
    out[(size_t)node * NCLASS + lane] = x - m - logf(ssum);
}

// ---------------- launch ----------------

extern "C" void kernel_launch(void* const* d_in, const int* in_sizes, int n_in,
                              void* d_out, int out_size, void* d_ws, size_t ws_size,
                              hipStream_t stream) {
    const float* x  = (const float*)d_in[0];   // [50000,512]
    const float* W1 = (const float*)d_in[1];   // [512,256]
    const float* b1 = (const float*)d_in[2];   // [256]
    const float* W2 = (const float*)d_in[3];   // [256,64]
    const float* b2 = (const float*)d_in[4];   // [64]
    const float* ew = (const float*)d_in[5];   // [800000]
    const int* esrc = (const int*)d_in[6];
    const int* edst = (const int*)d_in[7];
    float* out = (float*)d_out;                // [50000,64]

    char* ws = (char*)d_ws;
    size_t off = 0;
    auto take = [&](size_t bytes) -> void* {
        off = (off + 255) & ~(size_t)255;
        void* p = ws + off;
        off += bytes;
        return p;
    };
    u16* S1       = (u16*)take((size_t)N_NODES * NHID * 2);    // 25.6 MB
    u16* H        = (u16*)take((size_t)N_NODES * NHID * 2);    // 25.6 MB
    u16* S2       = (u16*)take((size_t)N_NODES * NCLASS * 2);  // 6.4 MB
    u16* W1T      = (u16*)take((size_t)NHID * NFEAT * 2);      // [256][512]
    u16* W2T      = (u16*)take((size_t)NCLASS * NHID * 2);     // [64][256]
    int* deg      = (int*)take((size_t)DEG_PAD * 4);
    int* rowstart = (int*)take((size_t)(N_NODES + 1) * 4);
    int* rank     = (int*)take((size_t)N_EDGES * 4);           // 3.2 MB
    u32* csr      = (u32*)take((size_t)N_EDGES * 4);           // 3.2 MB packed
    (void)ws_size; (void)in_sizes; (void)n_in; (void)out_size;

    hipMemsetAsync(deg, 0, (size_t)DEG_PAD * 4, stream);
    prep_kernel<<<967, 256, 0, stream>>>(W1, W1T, W2, W2T, edst, deg, rank);
    scan_kernel<<<1, 1024, 0, stream>>>(deg, rowstart, N_NODES);
    gemm1_scatter_kernel<<<GB1 + SB, 256, 0, stream>>>(x, W1T, S1, esrc, edst, ew,
                                                       rowstart, rank, csr);
    spmm_bias_relu_kernel<<<(N_NODES + 3) / 4, 256, 0, stream>>>(
        S1, rowstart, csr, b1, H, N_NODES);
    gemm2_kernel<<<(N_NODES + 127) / 128, 256, 0, stream>>>(H, W2T, S2, N_NODES);
    spmm_bias_lsm_kernel<<<(N_NODES + 3) / 4, 256, 0, stream>>>(
        S2, rowstart, csr, b2, out, N_NODES);
}